// Round 9
// baseline (127.586 us; speedup 1.0000x reference)
//
#include <hip/hip_runtime.h>
#include <hip/hip_bf16.h>
#include <stdint.h>

#define NHEADS 12
#define HS 64
#define NB 8
#define NL 1024
#define ND 768
#define NE 1536
#define INFV 1000000000000.0f

typedef __bf16 bf16x8 __attribute__((ext_vector_type(8)));
typedef float f32x4 __attribute__((ext_vector_type(4)));

typedef __attribute__((address_space(1))) const unsigned int gas_uint;
typedef __attribute__((address_space(3))) unsigned int las_uint;
#define GLOAD_LDS16(g, l) __builtin_amdgcn_global_load_lds((gas_uint*)(g), (las_uint*)(l), 16, 0, 0)

__device__ __forceinline__ unsigned short f2bf(float f) {
  unsigned int u = __builtin_bit_cast(unsigned int, f);
  u += 0x7fffu + ((u >> 16) & 1u);   // round-to-nearest-even
  return (unsigned short)(u >> 16);
}

__device__ __forceinline__ bf16x8 load_frag(const unsigned short* p) {
  uint4 v = *(const uint4*)p;
  return __builtin_bit_cast(bf16x8, v);
}

// ---- prep: W transpose->bf16 | rope trig table ----
__global__ __launch_bounds__(256) void k_prep(
    const float* __restrict__ W,
    unsigned short* __restrict__ wt,
    float* __restrict__ cst) {
  const int blk = blockIdx.x;
  if (blk < 288) {
    __shared__ float tile[64][65];
    int te = blk % 24, td = blk / 24;
    int c = threadIdx.x & 63, r4 = threadIdx.x >> 6;
    #pragma unroll
    for (int rr = 0; rr < 16; rr++) {
      int row = rr * 4 + r4;
      tile[row][c] = W[(size_t)(td * 64 + row) * NE + te * 64 + c];
    }
    __syncthreads();
    #pragma unroll
    for (int rr = 0; rr < 16; rr++) {
      int row = rr * 4 + r4;
      wt[(size_t)(te * 64 + row) * ND + td * 64 + c] = f2bf(tile[c][row]);
    }
  } else {
    int t = (blk - 288) * 256 + threadIdx.x;   // 32768 = 1024*32
    int p = t >> 5, i = t & 31;
    float inv = powf(10000.0f, -(float)i / 32.0f);
    float sv, cv;
    sincosf((float)p * inv, &sv, &cv);
    cst[(p * 32 + i) * 2 + 0] = cv;
    cst[(p * 32 + i) * 2 + 1] = sv;
  }
}

// ---- proj GEMM + RoPE (blocks 0..767) | below-diag fills (blocks 768+) ----
// Fill blocks have no LDS/barriers: their NT stores stream from separate
// wave contexts and overlap proj's MFMA/LDS phase (no shared vmcnt drain).
__global__ __launch_bounds__(256) void k_proj_fill(
    const float* __restrict__ x,             // [8192][768] fp32
    const unsigned short* __restrict__ wt,   // [1536][768] bf16 (W^T)
    const float* __restrict__ bias,          // [1536]
    const float* __restrict__ cst,           // [1024][32] float2 (c,s)
    unsigned short* __restrict__ qbuf, unsigned short* __restrict__ kbuf,
    const int* __restrict__ mask, float* __restrict__ out) {
  const int tid = threadIdx.x;

  if (blockIdx.x >= 768) {
    // ---- fill path: one below-diagonal 128x128 tile per block ----
    const int e   = blockIdx.x - 768;        // 0..2687
    const int bh  = e / 28;
    int u = e % 28;
    int tm = 1;
    #pragma unroll
    for (int k = 0; k < 6; k++) if (u >= tm) { u -= tm; tm++; }
    const int tn = u;                        // tn < tm
    const int b  = bh / NHEADS;
    const int* mrow = mask + b * NL;
    const int n0 = tn * 128 + (tid & 31) * 4;
    int4 mc = *(const int4*)&mrow[n0];
    float o0 = ((mc.x ? 0.0f : -INFV) - INFV) * 0.125f;  // mr==1 case
    float o1 = ((mc.y ? 0.0f : -INFV) - INFV) * 0.125f;
    float o2 = ((mc.z ? 0.0f : -INFV) - INFV) * 0.125f;
    float o3 = ((mc.w ? 0.0f : -INFV) - INFV) * 0.125f;
    const float oz = (-2.0f * INFV) * 0.125f;            // mr==0 => (-INF-INF)/8
    #pragma unroll
    for (int it = 0; it < 16; it++) {
      int m = tm * 128 + it * 8 + (tid >> 5);
      bool mr1 = (mrow[m] != 0);
      f32x4 o;
      o[0] = mr1 ? o0 : oz;
      o[1] = mr1 ? o1 : oz;
      o[2] = mr1 ? o2 : oz;
      o[3] = mr1 ? o3 : oz;
      __builtin_nontemporal_store(o, (f32x4*)(out + ((size_t)bh * NL + m) * NL + n0));
    }
    return;
  }

  // ---- proj path (identical core to round 8, minus in-loop fills) ----
  const int blk = blockIdx.x;
  const int xcd = blk & 7;
  const int loc = blk >> 3;
  const int h   = loc % 12;
  const int mt  = xcd * 8 + loc / 12;
  const int m0  = mt * 128;
  const int e0  = h * 128;
  const int lane = tid & 63;
  const int w    = tid >> 6;
  const int wm = w >> 1, wn = w & 1;
  const int col_l = lane & 15, rq = lane >> 4;

  __shared__ char smem_b[49152];             // A 16K | B 32K

  unsigned int goffA[4];
  #pragma unroll
  for (int q = 0; q < 4; q++) {
    int p = q * 256 + tid;
    int r = p >> 3, sl = p & 7;
    goffA[q] = r * ND + (sl ^ (r & 7)) * 8;  // bf16 elements
  }
  unsigned int goffB[8];
  #pragma unroll
  for (int q = 0; q < 8; q++) {
    int p = q * 256 + tid;
    int r = p >> 4, sl = p & 15;
    goffB[q] = r * ND + (sl ^ (r & 15)) * 4; // fp32 elements
  }
  const unsigned short* gA = wt + (size_t)e0 * ND;
  const float*          gB = x  + (size_t)m0 * ND;

  const int xr = col_l & 7;
  const unsigned int aRow = (unsigned)((wn * 64 + col_l) * 128);
  const unsigned int bRow = (unsigned)(16384 + (wm * 64 + col_l) * 256);

  f32x4 acc[4][4];   // [e-frag][m-frag]
  #pragma unroll
  for (int i = 0; i < 4; i++)
    #pragma unroll
    for (int j = 0; j < 4; j++)
      #pragma unroll
      for (int q = 0; q < 4; q++) acc[i][j][q] = 0.0f;

  for (int kk = 0; kk < ND; kk += 64) {
    const unsigned short* sA = gA + kk;
    const float*          sB = gB + kk;
    #pragma unroll
    for (int q = 0; q < 4; q++) GLOAD_LDS16(sA + goffA[q], smem_b + (q * 256 + tid) * 16);
    #pragma unroll
    for (int q = 0; q < 8; q++) GLOAD_LDS16(sB + goffB[q], smem_b + 16384 + (q * 256 + tid) * 16);
    __syncthreads();
    #pragma unroll
    for (int kkh = 0; kkh < 2; kkh++) {
      bf16x8 af[4], bfr[4];
      #pragma unroll
      for (int f = 0; f < 4; f++) {
        af[f] = __builtin_bit_cast(bf16x8,
            *(const uint4*)(smem_b + aRow + f * 2048 + (((kkh << 2) | rq) ^ xr) * 16));
        const int sl0 = (kkh << 3) | (rq << 1);
        float4 lo = *(const float4*)(smem_b + bRow + f * 4096 + ((sl0 ^ col_l) * 16));
        float4 hi = *(const float4*)(smem_b + bRow + f * 4096 + (((sl0 + 1) ^ col_l) * 16));
        bfr[f] = bf16x8{(__bf16)lo.x, (__bf16)lo.y, (__bf16)lo.z, (__bf16)lo.w,
                        (__bf16)hi.x, (__bf16)hi.y, (__bf16)hi.z, (__bf16)hi.w};
      }
      #pragma unroll
      for (int i = 0; i < 4; i++)
        #pragma unroll
        for (int j = 0; j < 4; j++)
          acc[i][j] = __builtin_amdgcn_mfma_f32_16x16x32_bf16(af[i], bfr[j], acc[i][j], 0, 0, 0);
    }
    __syncthreads();
  }

  // epilogue: bias + rope (in-thread pairs; one 16B trig load per frag)
  unsigned short* obuf = (wn == 1) ? kbuf : qbuf;   // wave-uniform
  #pragma unroll
  for (int j = 0; j < 4; j++) {
    const int m   = m0 + wm * 64 + j * 16 + col_l;
    const int pos = m & (NL - 1);
    const int bb  = m >> 10;
    const float* crow = cst + pos * 64;
    unsigned short* orow = obuf + (((size_t)(bb * NHEADS + h)) * NL + pos) * HS;
    #pragma unroll
    for (int i = 0; i < 4; i++) {
      const int s0 = i * 16 + rq * 4;
      float4 bv = *(const float4*)&bias[e0 + wn * 64 + s0];
      float4 tq = *(const float4*)(crow + s0);
      float v0 = acc[i][j][0] + bv.x;
      float v1 = acc[i][j][1] + bv.y;
      float v2 = acc[i][j][2] + bv.z;
      float v3 = acc[i][j][3] + bv.w;
      ushort4 o;
      o.x = f2bf(v0 * tq.x - v1 * tq.y);
      o.y = f2bf(v1 * tq.x + v0 * tq.y);
      o.z = f2bf(v2 * tq.z - v3 * tq.w);
      o.w = f2bf(v3 * tq.z + v2 * tq.w);
      *(ushort4*)&orow[s0] = o;
    }
  }
}

// ---- logits: upper-triangle (tn >= tm) tiles only, per (b,h) Q @ K^T ----
__global__ __launch_bounds__(256) void k_logits(
    const unsigned short* __restrict__ qbuf,
    const unsigned short* __restrict__ kbuf,
    const int* __restrict__ mask,
    float* __restrict__ out) {
  const int f  = blockIdx.x;
  const int r  = f & 7, t = f >> 3;
  const int bh = r + 8 * (t / 36);
  int u = t % 36;
  int tm = 0;
  #pragma unroll
  for (int k = 0; k < 7; k++) if (u >= 8 - tm) { u -= 8 - tm; tm++; }
  const int tn = tm + u;
  const int b  = bh / NHEADS;
  const int tid  = threadIdx.x;
  const int* mrow = mask + b * NL;

  const int lane = tid & 63;
  const int w    = tid >> 6;
  const int wm = w >> 1, wn = w & 1;
  const int m_base = tm * 128 + wm * 64;
  const int n_base = tn * 128 + wn * 64;
  const int col_l = lane & 15, rq = lane >> 4;
  const unsigned short* Q = qbuf + (size_t)bh * (NL * HS);
  const unsigned short* K = kbuf + (size_t)bh * (NL * HS);

  __shared__ float lds[64 * 132];            // +4 float row pad

  f32x4 acc[4][4];   // [n-frag][m-frag]
  #pragma unroll
  for (int i = 0; i < 4; i++)
    #pragma unroll
    for (int j = 0; j < 4; j++)
      #pragma unroll
      for (int q = 0; q < 4; q++) acc[i][j][q] = 0.0f;

  #pragma unroll
  for (int ks = 0; ks < 2; ks++) {
    bf16x8 ak[4], bq[4];
    #pragma unroll
    for (int ff = 0; ff < 4; ff++) {
      ak[ff] = load_frag(K + (size_t)(n_base + ff * 16 + col_l) * HS + ks * 32 + rq * 8);
      bq[ff] = load_frag(Q + (size_t)(m_base + ff * 16 + col_l) * HS + ks * 32 + rq * 8);
    }
    #pragma unroll
    for (int i = 0; i < 4; i++)
      #pragma unroll
      for (int j = 0; j < 4; j++)
        acc[i][j] = __builtin_amdgcn_mfma_f32_16x16x32_bf16(ak[i], bq[j], acc[i][j], 0, 0, 0);
  }

  const bool diag = (tn == tm);
  const int rb_row = tid >> 5;
  const int rb_c4  = (tid & 31) * 4;
  const int n_rb   = tn * 128 + rb_c4;
  int4 mc_rb = *(const int4*)&mrow[n_rb];
  const bool allmc = (mc_rb.x & mc_rb.y & mc_rb.z & mc_rb.w) != 0;

  #pragma unroll
  for (int pass = 0; pass < 2; pass++) {
    if (wm == pass) {
      #pragma unroll
      for (int j = 0; j < 4; j++) {
        const int rl = j * 16 + col_l;
        #pragma unroll
        for (int i = 0; i < 4; i++)
          *(f32x4*)&lds[rl * 132 + wn * 64 + i * 16 + rq * 4] = acc[i][j];
      }
    }
    __syncthreads();
    #pragma unroll
    for (int it = 0; it < 8; it++) {
      const int rl = it * 8 + rb_row;
      const int m  = tm * 128 + pass * 64 + rl;
      f32x4 v = *(const f32x4*)&lds[rl * 132 + rb_c4];
      if (mrow[m] == 0) { v[0] = -INFV; v[1] = -INFV; v[2] = -INFV; v[3] = -INFV; }
      if (!allmc) {
        if (mc_rb.x == 0) v[0] = -INFV;
        if (mc_rb.y == 0) v[1] = -INFV;
        if (mc_rb.z == 0) v[2] = -INFV;
        if (mc_rb.w == 0) v[3] = -INFV;
      }
      if (diag) {
        if (n_rb + 0 < m) v[0] -= INFV;
        if (n_rb + 1 < m) v[1] -= INFV;
        if (n_rb + 2 < m) v[2] -= INFV;
        if (n_rb + 3 < m) v[3] -= INFV;
      }
      v *= 0.125f;
      __builtin_nontemporal_store(v, (f32x4*)(out + ((size_t)bh * NL + m) * NL + n_rb));
    }
    __syncthreads();
  }
}

extern "C" void kernel_launch(void* const* d_in, const int* in_sizes, int n_in,
                              void* d_out, int out_size, void* d_ws, size_t ws_size,
                              hipStream_t stream) {
  const float* x    = (const float*)d_in[0];
  const float* W    = (const float*)d_in[1];
  const float* bias = (const float*)d_in[2];
  const int*   mask = (const int*)d_in[3];
  float* out = (float*)d_out;
  char* ws = (char*)d_ws;

  unsigned short* wt = (unsigned short*)(ws);              //  2,359,296 B
  unsigned short* qb = (unsigned short*)(ws + 2359296);    // 12,582,912 B
  unsigned short* kb = (unsigned short*)(ws + 14942208);   // 12,582,912 B
  float* cst = (float*)(ws + 27525120);                    //    262,144 B

  k_prep<<<416, 256, 0, stream>>>(W, wt, cst);
  k_proj_fill<<<768 + 2688, 256, 0, stream>>>(x, wt, bias, cst, qb, kb, mask, out);
  k_logits<<<3456, 256, 0, stream>>>(qb, kb, mask, out);
}

// Round 10
// 120.068 us; speedup vs baseline: 1.0626x; 1.0626x over previous
//
#include <hip/hip_runtime.h>
#include <hip/hip_bf16.h>
#include <stdint.h>

#define NHEADS 12
#define HS 64
#define NB 8
#define NL 1024
#define ND 768
#define NE 1536
#define INFV 1000000000000.0f

typedef __bf16 bf16x8 __attribute__((ext_vector_type(8)));
typedef float f32x4 __attribute__((ext_vector_type(4)));

typedef __attribute__((address_space(1))) const unsigned int gas_uint;
typedef __attribute__((address_space(3))) unsigned int las_uint;
#define GLOAD_LDS16(g, l) __builtin_amdgcn_global_load_lds((gas_uint*)(g), (las_uint*)(l), 16, 0, 0)

__device__ __forceinline__ unsigned short f2bf(float f) {
  unsigned int u = __builtin_bit_cast(unsigned int, f);
  u += 0x7fffu + ((u >> 16) & 1u);   // round-to-nearest-even
  return (unsigned short)(u >> 16);
}

__device__ __forceinline__ bf16x8 load_frag(const unsigned short* p) {
  uint4 v = *(const uint4*)p;
  return __builtin_bit_cast(bf16x8, v);
}

// ---- prep: x->bf16 | W transpose->bf16 | rope trig table ----
__global__ __launch_bounds__(256) void k_prep(
    const float* __restrict__ x, const float* __restrict__ W,
    unsigned short* __restrict__ xb, unsigned short* __restrict__ wt,
    float* __restrict__ cst) {
  const int blk = blockIdx.x;
  if (blk < 6144) {
    int i = blk * 256 + threadIdx.x;
    float4 v = ((const float4*)x)[i];
    ushort4 o;
    o.x = f2bf(v.x); o.y = f2bf(v.y); o.z = f2bf(v.z); o.w = f2bf(v.w);
    ((ushort4*)xb)[i] = o;
  } else if (blk < 6144 + 288) {
    __shared__ float tile[64][65];
    int t = blk - 6144;
    int te = t % 24, td = t / 24;
    int c = threadIdx.x & 63, r4 = threadIdx.x >> 6;
    #pragma unroll
    for (int rr = 0; rr < 16; rr++) {
      int row = rr * 4 + r4;
      tile[row][c] = W[(size_t)(td * 64 + row) * NE + te * 64 + c];
    }
    __syncthreads();
    #pragma unroll
    for (int rr = 0; rr < 16; rr++) {
      int row = rr * 4 + r4;
      wt[(size_t)(te * 64 + row) * ND + td * 64 + c] = f2bf(tile[c][row]);
    }
  } else {
    int t = (blk - 6432) * 256 + threadIdx.x;   // 32768 = 1024*32
    int p = t >> 5, i = t & 31;
    float inv = powf(10000.0f, -(float)i / 32.0f);
    float sv, cv;
    sincosf((float)p * inv, &sv, &cv);
    cst[(p * 32 + i) * 2 + 0] = cv;
    cst[(p * 32 + i) * 2 + 1] = sv;
  }
}

// ---- proj GEMM + RoPE (blocks 0..767) | below-diag fills (blocks 768+) ----
// 32 KB LDS (A,B bf16) + launch_bounds(256,4) => VGPR<=128 => 4 blocks/CU:
// 3 proj + 1 fill co-resident; fill NT-store streams hide under proj compute.
__global__ __launch_bounds__(256, 4) void k_proj_fill(
    const unsigned short* __restrict__ xb,   // [8192][768] bf16
    const unsigned short* __restrict__ wt,   // [1536][768] bf16 (W^T)
    const float* __restrict__ bias,          // [1536]
    const float* __restrict__ cst,           // [1024][32] float2 (c,s)
    unsigned short* __restrict__ qbuf, unsigned short* __restrict__ kbuf,
    const int* __restrict__ mask, float* __restrict__ out) {
  const int tid = threadIdx.x;

  __shared__ char smem_b[32768];             // A 16K | B 16K (bf16)

  if (blockIdx.x >= 768) {
    // ---- fill path: one below-diagonal 128x128 tile per block ----
    const int e   = blockIdx.x - 768;        // 0..2687
    const int bh  = e / 28;
    int u = e % 28;
    int tm = 1;
    #pragma unroll
    for (int k = 0; k < 6; k++) if (u >= tm) { u -= tm; tm++; }
    const int tn = u;                        // tn < tm
    const int b  = bh / NHEADS;
    const int* mrow = mask + b * NL;
    const int n0 = tn * 128 + (tid & 31) * 4;
    int4 mc = *(const int4*)&mrow[n0];
    float o0 = ((mc.x ? 0.0f : -INFV) - INFV) * 0.125f;  // mr==1 case
    float o1 = ((mc.y ? 0.0f : -INFV) - INFV) * 0.125f;
    float o2 = ((mc.z ? 0.0f : -INFV) - INFV) * 0.125f;
    float o3 = ((mc.w ? 0.0f : -INFV) - INFV) * 0.125f;
    const float oz = (-2.0f * INFV) * 0.125f;            // mr==0
    #pragma unroll
    for (int it = 0; it < 16; it++) {
      int m = tm * 128 + it * 8 + (tid >> 5);
      bool mr1 = (mrow[m] != 0);
      f32x4 o;
      o[0] = mr1 ? o0 : oz;
      o[1] = mr1 ? o1 : oz;
      o[2] = mr1 ? o2 : oz;
      o[3] = mr1 ? o3 : oz;
      __builtin_nontemporal_store(o, (f32x4*)(out + ((size_t)bh * NL + m) * NL + n0));
    }
    return;
  }

  // ---- proj path: A,B bf16 staged via gload_lds, XOR-swizzled ----
  const int blk = blockIdx.x;
  const int xcd = blk & 7;
  const int loc = blk >> 3;
  const int h   = loc % 12;
  const int mt  = xcd * 8 + loc / 12;
  const int m0  = mt * 128;
  const int e0  = h * 128;
  const int lane = tid & 63;
  const int w    = tid >> 6;
  const int wm = w >> 1, wn = w & 1;
  const int col_l = lane & 15, rq = lane >> 4;

  unsigned int goff[4];
  #pragma unroll
  for (int q = 0; q < 4; q++) {
    int p = q * 256 + tid;
    int r = p >> 3, sl = p & 7;
    goff[q] = r * ND + (sl ^ (r & 7)) * 8;   // bf16 elements, pre-swizzled src
  }
  const unsigned short* gA = wt + (size_t)e0 * ND;
  const unsigned short* gB = xb + (size_t)m0 * ND;

  const int xr = col_l & 7;
  const unsigned int aRow = (unsigned)((wn * 64 + col_l) * 128);
  const unsigned int bRow = (unsigned)(16384 + (wm * 64 + col_l) * 128);

  f32x4 acc[4][4];   // [e-frag][m-frag]
  #pragma unroll
  for (int i = 0; i < 4; i++)
    #pragma unroll
    for (int j = 0; j < 4; j++)
      #pragma unroll
      for (int q = 0; q < 4; q++) acc[i][j][q] = 0.0f;

  for (int kk = 0; kk < ND; kk += 64) {
    const unsigned short* sA = gA + kk;
    const unsigned short* sB = gB + kk;
    #pragma unroll
    for (int q = 0; q < 4; q++) GLOAD_LDS16(sA + goff[q], smem_b + (q * 256 + tid) * 16);
    #pragma unroll
    for (int q = 0; q < 4; q++) GLOAD_LDS16(sB + goff[q], smem_b + 16384 + (q * 256 + tid) * 16);
    __syncthreads();
    #pragma unroll
    for (int kkh = 0; kkh < 2; kkh++) {
      bf16x8 af[4], bfr[4];
      #pragma unroll
      for (int f = 0; f < 4; f++) {
        const unsigned int so = (((kkh << 2) | rq) ^ xr) * 16;
        af[f]  = __builtin_bit_cast(bf16x8, *(const uint4*)(smem_b + aRow + f * 2048 + so));
        bfr[f] = __builtin_bit_cast(bf16x8, *(const uint4*)(smem_b + bRow + f * 2048 + so));
      }
      #pragma unroll
      for (int i = 0; i < 4; i++)
        #pragma unroll
        for (int j = 0; j < 4; j++)
          acc[i][j] = __builtin_amdgcn_mfma_f32_16x16x32_bf16(af[i], bfr[j], acc[i][j], 0, 0, 0);
    }
    __syncthreads();
  }

  // epilogue: bias + rope (in-thread pairs; one 16B trig load per frag)
  unsigned short* obuf = (wn == 1) ? kbuf : qbuf;   // wave-uniform
  #pragma unroll
  for (int j = 0; j < 4; j++) {
    const int m   = m0 + wm * 64 + j * 16 + col_l;
    const int pos = m & (NL - 1);
    const int bb  = m >> 10;
    const float* crow = cst + pos * 64;
    unsigned short* orow = obuf + (((size_t)(bb * NHEADS + h)) * NL + pos) * HS;
    #pragma unroll
    for (int i = 0; i < 4; i++) {
      const int s0 = i * 16 + rq * 4;
      float4 bv = *(const float4*)&bias[e0 + wn * 64 + s0];
      float4 tq = *(const float4*)(crow + s0);
      float v0 = acc[i][j][0] + bv.x;
      float v1 = acc[i][j][1] + bv.y;
      float v2 = acc[i][j][2] + bv.z;
      float v3 = acc[i][j][3] + bv.w;
      ushort4 o;
      o.x = f2bf(v0 * tq.x - v1 * tq.y);
      o.y = f2bf(v1 * tq.x + v0 * tq.y);
      o.z = f2bf(v2 * tq.z - v3 * tq.w);
      o.w = f2bf(v3 * tq.z + v2 * tq.w);
      *(ushort4*)&orow[s0] = o;
    }
  }
}

// ---- logits: upper-triangle (tn >= tm) tiles only, per (b,h) Q @ K^T ----
__global__ __launch_bounds__(256) void k_logits(
    const unsigned short* __restrict__ qbuf,
    const unsigned short* __restrict__ kbuf,
    const int* __restrict__ mask,
    float* __restrict__ out) {
  const int f  = blockIdx.x;
  const int r  = f & 7, t = f >> 3;
  const int bh = r + 8 * (t / 36);
  int u = t % 36;
  int tm = 0;
  #pragma unroll
  for (int k = 0; k < 7; k++) if (u >= 8 - tm) { u -= 8 - tm; tm++; }
  const int tn = tm + u;
  const int b  = bh / NHEADS;
  const int tid  = threadIdx.x;
  const int* mrow = mask + b * NL;

  const int lane = tid & 63;
  const int w    = tid >> 6;
  const int wm = w >> 1, wn = w & 1;
  const int m_base = tm * 128 + wm * 64;
  const int n_base = tn * 128 + wn * 64;
  const int col_l = lane & 15, rq = lane >> 4;
  const unsigned short* Q = qbuf + (size_t)bh * (NL * HS);
  const unsigned short* K = kbuf + (size_t)bh * (NL * HS);

  __shared__ float lds[64 * 132];            // +4 float row pad

  f32x4 acc[4][4];   // [n-frag][m-frag]
  #pragma unroll
  for (int i = 0; i < 4; i++)
    #pragma unroll
    for (int j = 0; j < 4; j++)
      #pragma unroll
      for (int q = 0; q < 4; q++) acc[i][j][q] = 0.0f;

  #pragma unroll
  for (int ks = 0; ks < 2; ks++) {
    bf16x8 ak[4], bq[4];
    #pragma unroll
    for (int ff = 0; ff < 4; ff++) {
      ak[ff] = load_frag(K + (size_t)(n_base + ff * 16 + col_l) * HS + ks * 32 + rq * 8);
      bq[ff] = load_frag(Q + (size_t)(m_base + ff * 16 + col_l) * HS + ks * 32 + rq * 8);
    }
    #pragma unroll
    for (int i = 0; i < 4; i++)
      #pragma unroll
      for (int j = 0; j < 4; j++)
        acc[i][j] = __builtin_amdgcn_mfma_f32_16x16x32_bf16(ak[i], bq[j], acc[i][j], 0, 0, 0);
  }

  const bool diag = (tn == tm);
  const int rb_row = tid >> 5;
  const int rb_c4  = (tid & 31) * 4;
  const int n_rb   = tn * 128 + rb_c4;
  int4 mc_rb = *(const int4*)&mrow[n_rb];
  const bool allmc = (mc_rb.x & mc_rb.y & mc_rb.z & mc_rb.w) != 0;

  #pragma unroll
  for (int pass = 0; pass < 2; pass++) {
    if (wm == pass) {
      #pragma unroll
      for (int j = 0; j < 4; j++) {
        const int rl = j * 16 + col_l;
        #pragma unroll
        for (int i = 0; i < 4; i++)
          *(f32x4*)&lds[rl * 132 + wn * 64 + i * 16 + rq * 4] = acc[i][j];
      }
    }
    __syncthreads();
    #pragma unroll
    for (int it = 0; it < 8; it++) {
      const int rl = it * 8 + rb_row;
      const int m  = tm * 128 + pass * 64 + rl;
      f32x4 v = *(const f32x4*)&lds[rl * 132 + rb_c4];
      if (mrow[m] == 0) { v[0] = -INFV; v[1] = -INFV; v[2] = -INFV; v[3] = -INFV; }
      if (!allmc) {
        if (mc_rb.x == 0) v[0] = -INFV;
        if (mc_rb.y == 0) v[1] = -INFV;
        if (mc_rb.z == 0) v[2] = -INFV;
        if (mc_rb.w == 0) v[3] = -INFV;
      }
      if (diag) {
        if (n_rb + 0 < m) v[0] -= INFV;
        if (n_rb + 1 < m) v[1] -= INFV;
        if (n_rb + 2 < m) v[2] -= INFV;
        if (n_rb + 3 < m) v[3] -= INFV;
      }
      v *= 0.125f;
      __builtin_nontemporal_store(v, (f32x4*)(out + ((size_t)bh * NL + m) * NL + n_rb));
    }
    __syncthreads();
  }
}

extern "C" void kernel_launch(void* const* d_in, const int* in_sizes, int n_in,
                              void* d_out, int out_size, void* d_ws, size_t ws_size,
                              hipStream_t stream) {
  const float* x    = (const float*)d_in[0];
  const float* W    = (const float*)d_in[1];
  const float* bias = (const float*)d_in[2];
  const int*   mask = (const int*)d_in[3];
  float* out = (float*)d_out;
  char* ws = (char*)d_ws;

  unsigned short* xb = (unsigned short*)(ws);              // 12,582,912 B
  unsigned short* wt = (unsigned short*)(ws + 12582912);   //  2,359,296 B
  unsigned short* qb = (unsigned short*)(ws + 14942208);   // 12,582,912 B
  unsigned short* kb = (unsigned short*)(ws + 27525120);   // 12,582,912 B
  float* cst = (float*)(ws + 40108032);                    //    262,144 B

  k_prep<<<6560, 256, 0, stream>>>(x, W, xb, wt, cst);
  k_proj_fill<<<768 + 2688, 256, 0, stream>>>(xb, wt, bias, cst, qb, kb, mask, out);
  k_logits<<<3456, 256, 0, stream>>>(qb, kb, mask, out);
}